// Round 7
// baseline (89.606 us; speedup 1.0000x reference)
//
#include <hip/hip_runtime.h>
#include <math.h>

#define BB 4
#define PP 24
#define NN 3072
#define SS 128
#define CHUNK 512
#define NSPLIT 6             // NN / CHUNK
#define GRID (BB * PP * NSPLIT)   // 576
#define FINF 3.4e38f

// ws layout (floats):
//   [SMIN_F, +96*128*8)   : per-(bp,s) split mins, slot (bp*128+s)*8 + split (2 pad)
//   [SCAL_F, +96*6*4)     : per-(bp,split) scalars {pcl, cub, asum, pad}
//   [BPRES_F, +96*4)      : per-bp results {prim, pcl, cub, asum}
//   [CNT_F, +97)          : 96 per-bp counters + 1 global counter (zeroed each launch)
#define SMIN_F  0
#define SCAL_F  (96 * SS * 8)            // 98304
#define BPRES_F (SCAL_F + 96 * NSPLIT * 4)
#define CNT_F   (BPRES_F + 96 * 4)

__device__ __forceinline__ float fexp_f(float v, float p) {
    float m = powf(fabsf(v), p);
    float s = (v > 0.f) ? 1.f : ((v < 0.f) ? -1.f : 0.f);
    return s * m;
}
__device__ __forceinline__ float fix_f(float v) {
    return ((v > 0.f) ? 1.f : -1.f) * fmaxf(fabsf(v), 1e-6f);
}
__device__ __forceinline__ float wave_sum(float v) {
    #pragma unroll
    for (int off = 32; off > 0; off >>= 1) v += __shfl_down(v, off);
    return v;
}
__device__ __forceinline__ float aload(const float* p) {
    return __hip_atomic_load(p, __ATOMIC_RELAXED, __HIP_MEMORY_SCOPE_AGENT);
}
__device__ __forceinline__ void astore(float* p, float v) {
    __hip_atomic_store(p, v, __ATOMIC_RELAXED, __HIP_MEMORY_SCOPE_AGENT);
}
__device__ __forceinline__ float cub_dist(float px, float py, float pz,
                                          float nx, float ny, float nz,
                                          float sc0, float sc1, float sc2) {
    // argmax over {-nx,nx,-ny,ny,-nz,nz}; strict > == jnp first-max rule
    float best = -nx; int idx = 0;
    if ( nx > best) { best =  nx; idx = 1; }
    if (-ny > best) { best = -ny; idx = 2; }
    if ( ny > best) { best =  ny; idx = 3; }
    if (-nz > best) { best = -nz; idx = 4; }
    if ( nz > best) { best =  nz; idx = 5; }
    const int c = idx >> 1;
    const float scc = (c == 0) ? sc0 : ((c == 1) ? sc1 : sc2);
    const float fv  = (idx & 1) ? scc : -scc;
    float pr0 = (c == 0) ? fv : fminf(fmaxf(px, -sc0), sc0);
    float pr1 = (c == 1) ? fv : fminf(fmaxf(py, -sc1), sc1);
    float pr2 = (c == 2) ? fv : fminf(fmaxf(pz, -sc2), sc2);
    float d0 = pr0 - px, d1 = pr1 - py, d2 = pr2 - pz;
    return fmaf(d0, d0, fmaf(d1, d1, d2 * d2));
}

// ---- init: zero the 97 counters only ----
__global__ __launch_bounds__(128) void superdec_init(float* __restrict__ ws) {
    const int i = threadIdx.x;
    if (i < 97) ((unsigned*)(ws + CNT_F))[i] = 0u;
}

// ---- Fused kernel: 576 blocks x 256 threads.
// ---- Register-tiled single-D-eval: 64 ptgroups (8 pts) x 4 sgroups (32 s).
// ---- D = |x|^2 - 2x.p + |p|^2. Per-point path reduces (|x|^2-2x.p) (+|p|^2 later);
// ---- per-s path reduces (dA + |p|^2) directly (|p|^2 varies per point!).
// ---- Hierarchical finish identical to the verified round-5 structure.
__global__ __launch_bounds__(256) void superdec_fused(
    const float* __restrict__ pc, const float* __restrict__ nrm,
    const float* __restrict__ scale, const float* __restrict__ shape,
    const float* __restrict__ exist, const float* __restrict__ assign,
    const float* __restrict__ etas, const float* __restrict__ omegas,
    float* __restrict__ ws, float* __restrict__ out)
{
    const int blk   = blockIdx.x;
    const int bp    = blk / NSPLIT;
    const int split = blk % NSPLIT;
    const int b     = bp / PP;
    const int p     = bp % PP;
    const int tid   = threadIdx.x;
    const int n0    = split * CHUNK;
    const int pg    = tid & 63;    // point-group: points pg*8 .. pg*8+7
    const int sg    = tid >> 6;    // wave/sgroup: s in [sg*32, sg*32+32)

    __shared__ float4 Xs[SS];            // (-2x, -2y, -2z, |x|^2)
    __shared__ float  s_red[4][32][68];  // per-(sg,k): 64 pg partial s-mins (16B-aligned rows)
    __shared__ float4 dminL[4][64][2];   // per-(sg,pg): 8 per-point partial mins
    __shared__ float4 cubam[128][2];     // per pid: {cub0..3}, {am0..3}
    __shared__ float  red[1024];         // finisher scratch (same indices as round 5)
    __shared__ float  wsum[6];
    __shared__ unsigned s_cnt1, s_cnt2;

    const float sc0 = scale[bp * 3 + 0];
    const float sc1 = scale[bp * 3 + 1];
    const float sc2 = scale[bp * 3 + 2];

    // ---- every thread: its 8 tile points (6 contiguous float4) + |p|^2 ----
    const float4* pc4 = (const float4*)(pc + ((size_t)bp * NN + n0) * 3);
    float px[8], py[8], pz[8], psq[8];
    {
        const float4 g0 = pc4[pg * 6 + 0];
        const float4 g1 = pc4[pg * 6 + 1];
        const float4 g2 = pc4[pg * 6 + 2];
        const float4 g3 = pc4[pg * 6 + 3];
        const float4 g4 = pc4[pg * 6 + 4];
        const float4 g5 = pc4[pg * 6 + 5];
        px[0]=g0.x; py[0]=g0.y; pz[0]=g0.z;
        px[1]=g0.w; py[1]=g1.x; pz[1]=g1.y;
        px[2]=g1.z; py[2]=g1.w; pz[2]=g2.x;
        px[3]=g2.y; py[3]=g2.z; pz[3]=g2.w;
        px[4]=g3.x; py[4]=g3.y; pz[4]=g3.z;
        px[5]=g3.w; py[5]=g4.x; pz[5]=g4.y;
        px[6]=g4.z; py[6]=g4.w; pz[6]=g5.x;
        px[7]=g5.y; py[7]=g5.z; pz[7]=g5.w;
        #pragma unroll
        for (int j = 0; j < 8; ++j)
            psq[j] = fmaf(px[j], px[j], fmaf(py[j], py[j], pz[j] * pz[j]));
    }

    // ---- every thread: the OLD pid-based 4 points (for ps / cuboid; L1-hot) ----
    const int pid = tid & 127;
    const float4 a0 = pc4[pid * 3 + 0];
    const float4 a1 = pc4[pid * 3 + 1];
    const float4 a2 = pc4[pid * 3 + 2];
    const float qx0 = a0.x, qy0 = a0.y, qz0 = a0.z;
    const float qx1 = a0.w, qy1 = a1.x, qz1 = a1.y;
    const float qx2 = a1.z, qy2 = a1.w, qz2 = a2.x;
    const float qx3 = a2.y, qy3 = a2.z, qz3 = a2.w;
    const float qs0 = fmaf(qx0, qx0, fmaf(qy0, qy0, qz0 * qz0));
    const float qs1 = fmaf(qx1, qx1, fmaf(qy1, qy1, qz1 * qz1));
    const float qs2 = fmaf(qx2, qx2, fmaf(qy2, qy2, qz2 * qz2));
    const float qs3 = fmaf(qx3, qx3, fmaf(qy3, qy3, qz3 * qz3));

    if (tid < 128) {
        // waves 0,1: superquadric samples (identical formula/order to round 0)
        const float e1 = shape[bp * 2 + 0];
        const float e2 = shape[bp * 2 + 1];
        float eta = etas[bp * SS + tid];
        float omg = omegas[bp * SS + tid];
        eta = (eta == 0.f) ? 1e-6f : eta;
        omg = (omg == 0.f) ? 1e-6f : omg;
        float ce = cosf(eta), se = sinf(eta);
        float co = cosf(omg), so = sinf(omg);
        float fce = fexp_f(ce, e1);
        float x = fix_f(sc0 * fce * fexp_f(co, e2));
        float y = fix_f(sc1 * fce * fexp_f(so, e2));
        float z = fix_f(sc2 * fexp_f(se, e1));
        float xsq = fmaf(x, x, fmaf(y, y, z * z));
        Xs[tid] = make_float4(-2.f * x, -2.f * y, -2.f * z, xsq);
    } else {
        // waves 2,3: cuboid + assign for pid (identical formulas; values to LDS)
        const float4* nr4 = (const float4*)(nrm + ((size_t)bp * NN + n0) * 3);
        const float4 h0 = nr4[pid * 3 + 0];
        const float4 h1 = nr4[pid * 3 + 1];
        const float4 h2 = nr4[pid * 3 + 2];
        float c0 = cub_dist(qx0, qy0, qz0, h0.x, h0.y, h0.z, sc0, sc1, sc2);
        float c1 = cub_dist(qx1, qy1, qz1, h0.w, h1.x, h1.y, sc0, sc1, sc2);
        float c2 = cub_dist(qx2, qy2, qz2, h1.z, h1.w, h2.x, sc0, sc1, sc2);
        float c3 = cub_dist(qx3, qy3, qz3, h2.y, h2.z, h2.w, sc0, sc1, sc2);
        const size_t abase = ((size_t)b * NN + n0 + pid * 4) * PP + p;
        const float m0 = assign[abase + 0 * PP];
        const float m1 = assign[abase + 1 * PP];
        const float m2 = assign[abase + 2 * PP];
        const float m3 = assign[abase + 3 * PP];
        cubam[pid][0] = make_float4(c0, c1, c2, c3);
        cubam[pid][1] = make_float4(m0, m1, m2, m3);
    }
    __syncthreads();

    // ---- Pass A (single eval of D): 8 pts x 32 s per thread ----
    // dA_j = |x|^2 - 2x.p_j  (x.w folded into the fma chain)
    // per-point: pmin_j = min_s dA_j           (+|p_j|^2 later)
    // per-s:     sv     = min_j (dA_j + psq_j) (== |x-p|^2; published directly)
    {
        float pmin[8];
        #pragma unroll
        for (int j = 0; j < 8; ++j) pmin[j] = FINF;
        const int sb = sg * 32;
        #pragma unroll 4
        for (int k = 0; k < 32; ++k) {
            const float4 x = Xs[sb + k];
            float d0 = fmaf(x.x, px[0], fmaf(x.y, py[0], fmaf(x.z, pz[0], x.w)));
            float d1 = fmaf(x.x, px[1], fmaf(x.y, py[1], fmaf(x.z, pz[1], x.w)));
            float d2 = fmaf(x.x, px[2], fmaf(x.y, py[2], fmaf(x.z, pz[2], x.w)));
            float d3 = fmaf(x.x, px[3], fmaf(x.y, py[3], fmaf(x.z, pz[3], x.w)));
            float d4 = fmaf(x.x, px[4], fmaf(x.y, py[4], fmaf(x.z, pz[4], x.w)));
            float d5 = fmaf(x.x, px[5], fmaf(x.y, py[5], fmaf(x.z, pz[5], x.w)));
            float d6 = fmaf(x.x, px[6], fmaf(x.y, py[6], fmaf(x.z, pz[6], x.w)));
            float d7 = fmaf(x.x, px[7], fmaf(x.y, py[7], fmaf(x.z, pz[7], x.w)));
            pmin[0] = fminf(pmin[0], d0);
            pmin[1] = fminf(pmin[1], d1);
            pmin[2] = fminf(pmin[2], d2);
            pmin[3] = fminf(pmin[3], d3);
            pmin[4] = fminf(pmin[4], d4);
            pmin[5] = fminf(pmin[5], d5);
            pmin[6] = fminf(pmin[6], d6);
            pmin[7] = fminf(pmin[7], d7);
            const float e0 = d0 + psq[0], e1 = d1 + psq[1];
            const float e2 = d2 + psq[2], e3 = d3 + psq[3];
            const float e4 = d4 + psq[4], e5 = d5 + psq[5];
            const float e6 = d6 + psq[6], e7 = d7 + psq[7];
            const float sv = fminf(fminf(fminf(e0, e1), fminf(e2, e3)),
                                   fminf(fminf(e4, e5), fminf(e6, e7)));
            s_red[sg][k][pg] = sv;
        }
        dminL[sg][pg][0] = make_float4(pmin[0], pmin[1], pmin[2], pmin[3]);
        dminL[sg][pg][1] = make_float4(pmin[4], pmin[5], pmin[6], pmin[7]);
    }
    __syncthreads();

    // ---- publish per-s split min + per-point combine / pcl stage ----
    if (tid < SS) {
        // s = tid: min over the 64 pg partials of this s (already true distances)
        const int zg = tid >> 5, k = tid & 31;
        const float4* r4 = (const float4*)&s_red[zg][k][0];
        float m = FINF;
        #pragma unroll
        for (int i = 0; i < 16; ++i) {
            const float4 v = r4[i];
            m = fminf(fminf(fminf(m, v.x), v.y), fminf(v.z, v.w));
        }
        astore(ws + SMIN_F + ((bp * SS + tid) << 3) + split, m);

        // per-point min over the 4 sgroups, then the round-0 weighting stage
        const int pg2 = tid >> 1, hf = tid & 1;
        const float4 e0 = dminL[0][pg2][hf];
        const float4 e1 = dminL[1][pg2][hf];
        const float4 e2 = dminL[2][pg2][hf];
        const float4 e3 = dminL[3][pg2][hf];
        const float dd0 = fminf(fminf(e0.x, e1.x), fminf(e2.x, e3.x)) + qs0;
        const float dd1 = fminf(fminf(e0.y, e1.y), fminf(e2.y, e3.y)) + qs1;
        const float dd2 = fminf(fminf(e0.z, e1.z), fminf(e2.z, e3.z)) + qs2;
        const float dd3 = fminf(fminf(e0.w, e1.w), fminf(e2.w, e3.w)) + qs3;
        const float4 cb = cubam[tid][0];
        const float4 am = cubam[tid][1];
        const float acc_pcl = dd0 * am.x + dd1 * am.y + dd2 * am.z + dd3 * am.w;
        const float acc_cub = cb.x * am.x + cb.y * am.y + cb.z * am.z + cb.w * am.w;
        const float acc_am  = am.x + am.y + am.z + am.w;
        const float s0 = wave_sum(acc_pcl);
        const float s1 = wave_sum(acc_cub);
        const float s2 = wave_sum(acc_am);
        const int lane_ = tid & 63, wv = tid >> 6;   // wave 0 or 1
        if (lane_ == 0) {
            wsum[wv * 3 + 0] = s0;
            wsum[wv * 3 + 1] = s1;
            wsum[wv * 3 + 2] = s2;
        }
    }

    // ---- handoff (identical to round 5): barrier drains vmcnt, tid0 publishes
    // ---- scalars + bumps per-bp counter; 6th split-block finishes the bp.
    __syncthreads();
    if (tid == 0) {
        float* sc = ws + SCAL_F + (bp * NSPLIT + split) * 4;
        astore(sc + 0, wsum[0] + wsum[3]);
        astore(sc + 1, wsum[1] + wsum[4]);
        astore(sc + 2, wsum[2] + wsum[5]);
        asm volatile("s_waitcnt vmcnt(0)" ::: "memory");
        s_cnt1 = __hip_atomic_fetch_add((unsigned*)(ws + CNT_F) + bp, 1u,
                                        __ATOMIC_RELAXED, __HIP_MEMORY_SCOPE_AGENT);
    }
    __syncthreads();
    if (s_cnt1 != (unsigned)(NSPLIT - 1)) return;

    // ======== per-bp finisher (96 blocks, overlapped) — round-5 verified ========
    {
        const int lane = tid & 63;
        if (tid < SS) {                       // waves 0,1: s = tid
            const float* mb = ws + SMIN_F + ((bp * SS + tid) << 3);
            const float v0 = aload(mb + 0), v1 = aload(mb + 1), v2 = aload(mb + 2);
            const float v3 = aload(mb + 3), v4 = aload(mb + 4), v5 = aload(mb + 5);
            float m = fminf(fminf(fminf(v0, v1), fminf(v2, v3)), fminf(v4, v5));
            float sm = wave_sum(m);           // 64 consecutive s per wave
            if (lane == 0) wsum[tid >> 6] = sm;
        } else if (tid < 128 + 18) {          // wave 2: 18 scalar loads in parallel
            const int j = tid - 128, sp = j / 3, c = j % 3;
            red[600 + j] = aload(ws + SCAL_F + (bp * NSPLIT + sp) * 4 + c);
        }
        __syncthreads();
        if (tid == 0) {
            const float prim = wsum[0] + wsum[1];
            float pcl = 0.f, cubv = 0.f, cs = 0.f;
            #pragma unroll
            for (int sp = 0; sp < NSPLIT; ++sp) {
                pcl  += red[600 + sp * 3 + 0];
                cubv += red[600 + sp * 3 + 1];
                cs   += red[600 + sp * 3 + 2];
            }
            float* r4 = ws + BPRES_F + bp * 4;
            astore(r4 + 0, prim);
            astore(r4 + 1, pcl);
            astore(r4 + 2, cubv);
            astore(r4 + 3, cs);
            asm volatile("s_waitcnt vmcnt(0)" ::: "memory");
            s_cnt2 = __hip_atomic_fetch_add((unsigned*)(ws + CNT_F) + 96, 1u,
                                            __ATOMIC_RELAXED, __HIP_MEMORY_SCOPE_AGENT);
        }
        __syncthreads();
        if (s_cnt2 != 95u) return;
    }

    // ======== global final (single block) — round-5 verified ========
    if (tid < 96) {
        const float* r4 = ws + BPRES_F + tid * 4;
        const float prim = aload(r4 + 0);
        const float pcl  = aload(r4 + 1);
        const float cubv = aload(r4 + 2);
        const float cs   = aload(r4 + 3);
        const float e  = exist[tid];
        const float gt = (cs > 24.0f) ? 1.f : 0.f;
        red[  0 + tid] = prim;
        red[ 96 + tid] = pcl;
        red[192 + tid] = cubv;
        red[288 + tid] = gt * logf(e) + (1.f - gt) * log1pf(-e);
        red[384 + tid] = e;
        red[480 + tid] = sqrtf(cs / (float)NN + 0.01f);
    }
    __syncthreads();

    if (tid == 0) {
        float pcl_sum = 0.f, cub_sum = 0.f, bce_sum = 0.f, prim_loss = 0.f, sps = 0.f;
        #pragma unroll
        for (int b_ = 0; b_ < BB; ++b_) {
            float pe = 0.f, ee = 0.f, sq = 0.f;
            #pragma unroll
            for (int p_ = 0; p_ < PP; ++p_) {
                const int i = b_ * PP + p_;
                pcl_sum += red[ 96 + i];
                cub_sum += red[192 + i];
                bce_sum += red[288 + i];
                pe += (red[i] / (float)SS) * red[384 + i];
                ee += red[384 + i];
                sq += red[480 + i];
            }
            prim_loss += pe / (ee + 1e-6f);
            float mb = sq / (float)PP;
            sps += mb * mb;
        }
        prim_loss /= (float)BB;
        sps       /= (float)BB;
        float pcl_loss = pcl_sum / (float)(BB * NN);
        float cubf     = cub_sum / (float)(BB * NN);
        float bce      = -bce_sum / (float)(BB * PP);
        out[0] = 0.1f * cubf + 1.0f * (pcl_loss + prim_loss) + 0.01f * bce + 0.01f * sps;
    }
}

extern "C" void kernel_launch(void* const* d_in, const int* in_sizes, int n_in,
                              void* d_out, int out_size, void* d_ws, size_t ws_size,
                              hipStream_t stream) {
    const float* pc     = (const float*)d_in[0];
    const float* nrm    = (const float*)d_in[1];
    const float* scale  = (const float*)d_in[2];
    const float* shape  = (const float*)d_in[3];
    const float* exist  = (const float*)d_in[4];
    const float* assign = (const float*)d_in[5];
    const float* etas   = (const float*)d_in[6];
    const float* omegas = (const float*)d_in[7];
    float* ws  = (float*)d_ws;
    float* out = (float*)d_out;

    // zero the 97 counters (ws is poisoned by the harness each iteration)
    superdec_init<<<1, 128, 0, stream>>>(ws);

    superdec_fused<<<GRID, 256, 0, stream>>>(
        pc, nrm, scale, shape, exist, assign, etas, omegas, ws, out);
}